// Round 1
// baseline (1498.575 us; speedup 1.0000x reference)
//
#include <hip/hip_runtime.h>

#define NPTS 16384
#define P 8
#define NU (1.0f / 100.0f)

// 6-channel forward-mode propagation:
//   c=0: value, c=1: d/dt, c=2: d/dx, c=3: d/dy, c=4: d2/dx2, c=5: d2/dy2
// State s[(c*P+p)*256 + j] in LDS (48 KB). Thread j owns output neuron j.

__global__ __launch_bounds__(256) void pinn_ns_kernel(
    const float* __restrict__ t_, const float* __restrict__ x_, const float* __restrict__ y_,
    const float* __restrict__ W0, const float* __restrict__ b0,
    const float* __restrict__ W1, const float* __restrict__ b1,
    const float* __restrict__ W2, const float* __restrict__ b2,
    const float* __restrict__ W3, const float* __restrict__ b3,
    const float* __restrict__ W4, const float* __restrict__ b4,
    const float* __restrict__ W5, const float* __restrict__ b5,
    const float* __restrict__ W6, const float* __restrict__ b6,
    float* __restrict__ out)
{
    __shared__ __align__(16) float s[48 * 256];
    __shared__ __align__(16) float w6t[3][256];
    __shared__ float res[P][6][3];
    __shared__ float txy[3][P];

    const int tid = threadIdx.x;
    const int p0 = blockIdx.x * P;

    if (tid < 3 * P) {
        int c = tid >> 3, p = tid & 7;
        const float* src = (c == 0) ? t_ : (c == 1) ? x_ : y_;
        txy[c][p] = src[p0 + p];
    }
    // W6 transposed into LDS: w6t[o][k] = W6[k][o]
    #pragma unroll
    for (int o = 0; o < 3; ++o) w6t[o][tid] = W6[tid * 3 + o];
    __syncthreads();

    // ---- layer 0: 3 -> 256, sin.  z_t=W0[0][j], z_x=W0[1][j], z_y=W0[2][j], z_xx=z_yy=0
    {
        float wt = W0[tid], wx = W0[256 + tid], wy = W0[512 + tid];
        float bb = b0[tid];
        #pragma unroll
        for (int p = 0; p < P; ++p) {
            float z = txy[0][p] * wt + txy[1][p] * wx + txy[2][p] * wy + bb;
            float sv, cv;
            __sincosf(z, &sv, &cv);
            s[(0 * P + p) * 256 + tid] = sv;
            s[(1 * P + p) * 256 + tid] = cv * wt;
            s[(2 * P + p) * 256 + tid] = cv * wx;
            s[(3 * P + p) * 256 + tid] = cv * wy;
            s[(4 * P + p) * 256 + tid] = -sv * wx * wx;
            s[(5 * P + p) * 256 + tid] = -sv * wy * wy;
        }
    }
    __syncthreads();

    // ---- layers 1..5: 256 -> 256, sin
    const float* Ws[5] = {W1, W2, W3, W4, W5};
    const float* bs[5] = {b1, b2, b3, b4, b5};
    for (int L = 0; L < 5; ++L) {
        const float* __restrict__ W = Ws[L];
        float acc[48];
        #pragma unroll
        for (int i = 0; i < 48; ++i) acc[i] = 0.f;

        for (int kb = 0; kb < 64; ++kb) {
            float w0 = W[(4 * kb + 0) * 256 + tid];
            float w1 = W[(4 * kb + 1) * 256 + tid];
            float w2 = W[(4 * kb + 2) * 256 + tid];
            float w3 = W[(4 * kb + 3) * 256 + tid];
            #pragma unroll
            for (int pc = 0; pc < 48; ++pc) {
                const float4 h = *(const float4*)&s[pc * 256 + 4 * kb];
                acc[pc] += h.x * w0 + h.y * w1 + h.z * w2 + h.w * w3;
            }
        }

        float bb = bs[L][tid];
        __syncthreads();  // all reads of s done before overwrite
        #pragma unroll
        for (int p = 0; p < P; ++p) {
            float z   = acc[0 * P + p] + bb;
            float zt  = acc[1 * P + p], zx = acc[2 * P + p], zy = acc[3 * P + p];
            float zxx = acc[4 * P + p], zyy = acc[5 * P + p];
            float sv, cv;
            __sincosf(z, &sv, &cv);
            s[(0 * P + p) * 256 + tid] = sv;
            s[(1 * P + p) * 256 + tid] = cv * zt;
            s[(2 * P + p) * 256 + tid] = cv * zx;
            s[(3 * P + p) * 256 + tid] = cv * zy;
            s[(4 * P + p) * 256 + tid] = cv * zxx - sv * zx * zx;
            s[(5 * P + p) * 256 + tid] = cv * zyy - sv * zy * zy;
        }
        __syncthreads();
    }

    // ---- layer 6: 256 -> 3 linear.  144 dot products: (p, c, o)
    if (tid < 144) {
        int p = tid / 18, r = tid % 18, c = r / 3, o = r % 3;
        int X = c * P + p;
        const float4* hs = (const float4*)&s[X * 256];
        const float4* wv = (const float4*)&w6t[o][0];
        float accd = 0.f;
        for (int kb = 0; kb < 64; ++kb) {
            int k = (kb + X) & 63;  // stagger to spread LDS banks
            float4 h = hs[k], w = wv[k];
            accd += h.x * w.x + h.y * w.y + h.z * w.z + h.w * w.w;
        }
        if (c == 0) accd += b6[o];
        res[p][c][o] = accd;
    }
    __syncthreads();

    if (tid < P) {
        int p = tid, g = p0 + p;
        float u   = res[p][0][0], v   = res[p][0][1];
        float ut  = res[p][1][0], vt  = res[p][1][1];
        float ux  = res[p][2][0], vx  = res[p][2][1], px = res[p][2][2];
        float uy  = res[p][3][0], vy  = res[p][3][1], py = res[p][3][2];
        float uxx = res[p][4][0], vxx = res[p][4][1];
        float uyy = res[p][5][0], vyy = res[p][5][1];
        out[g]            = ut + (u * ux + v * uy) + px - NU * (uxx + uyy);
        out[NPTS + g]     = vt + (u * vx + v * vy) + py - NU * (vxx + vyy);
        out[2 * NPTS + g] = ux + vy;
    }
}

extern "C" void kernel_launch(void* const* d_in, const int* in_sizes, int n_in,
                              void* d_out, int out_size, void* d_ws, size_t ws_size,
                              hipStream_t stream) {
    const float* t_ = (const float*)d_in[0];
    const float* x_ = (const float*)d_in[1];
    const float* y_ = (const float*)d_in[2];
    const float* W[7];
    const float* b[7];
    for (int i = 0; i < 7; ++i) {
        W[i] = (const float*)d_in[3 + 2 * i];
        b[i] = (const float*)d_in[4 + 2 * i];
    }
    float* out = (float*)d_out;
    dim3 grid(NPTS / P), block(256);
    hipLaunchKernelGGL(pinn_ns_kernel, grid, block, 0, stream,
                       t_, x_, y_,
                       W[0], b[0], W[1], b[1], W[2], b[2], W[3], b[3],
                       W[4], b[4], W[5], b[5], W[6], b[6], out);
}

// Round 2
// 250.610 us; speedup vs baseline: 5.9797x; 5.9797x over previous
//
#include <hip/hip_runtime.h>

#define NPTS 16384
#define PW 16
#define NU (1.0f / 100.0f)

typedef __attribute__((ext_vector_type(8))) short bf16x8;
typedef __attribute__((ext_vector_type(4))) float f32x4;
typedef __attribute__((ext_vector_type(4))) unsigned int u32x4;

__device__ __forceinline__ unsigned short f2bf(float f) {
    unsigned u = __builtin_bit_cast(unsigned, f);
    u += 0x7fffu + ((u >> 16) & 1u);   // round-to-nearest-even
    return (unsigned short)(u >> 16);
}
__device__ __forceinline__ float bf2f(unsigned short h) {
    unsigned u = ((unsigned)h) << 16;
    return __builtin_bit_cast(float, u);
}

// ---- prep: repack W1..W5 (256x256) and W6 (256x3, zero-padded to 16 cols)
// into MFMA B-fragment order, split into bf16 hi/lo planes.
// B-frag (16x16x32): lane l holds B[k = kc*32 + 8*(l>>4)+j][n = nf*16 + (l&15)], j=0..7 contiguous.
__global__ __launch_bounds__(256) void prep_kernel(
    const float* __restrict__ W1, const float* __restrict__ W2,
    const float* __restrict__ W3, const float* __restrict__ W4,
    const float* __restrict__ W5, const float* __restrict__ W6,
    unsigned short* __restrict__ bhi, unsigned short* __restrict__ blo,
    unsigned short* __restrict__ b6hi, unsigned short* __restrict__ b6lo)
{
    int idx = blockIdx.x * 256 + threadIdx.x;
    if (idx < 5 * 65536) {
        int L = idx >> 16, u = idx & 65535;
        int j = u & 7, lane = (u >> 3) & 63, nf = (u >> 9) & 15, kc = u >> 13;
        int k = kc * 32 + 8 * (lane >> 4) + j;
        int n = nf * 16 + (lane & 15);
        const float* W = (L == 0) ? W1 : (L == 1) ? W2 : (L == 2) ? W3 : (L == 3) ? W4 : W5;
        float w = W[k * 256 + n];
        unsigned short h = f2bf(w);
        bhi[idx] = h;
        blo[idx] = f2bf(w - bf2f(h));
    } else {
        int u = idx - 5 * 65536;
        if (u < 4096) {
            int j = u & 7, lane = (u >> 3) & 63, kc = u >> 9;
            int k = kc * 32 + 8 * (lane >> 4) + j;
            int n = lane & 15;
            float w = (n < 3) ? W6[k * 3 + n] : 0.f;
            unsigned short h = f2bf(w);
            b6hi[u] = h;
            b6lo[u] = f2bf(w - bf2f(h));
        }
    }
}

// ---- main: P=16 points/block, state rows = c*16+p (c: 0=val,1=dt,2=dx,3=dy,4=dxx,5=dyy)
// 8 waves; each wave: all 6 m-frags x 2 n-frags (32-col stripe).
__global__ __launch_bounds__(512) void pinn_ns_mfma(
    const float* __restrict__ t_, const float* __restrict__ x_, const float* __restrict__ y_,
    const float* __restrict__ W0, const float* __restrict__ b0,
    const float* __restrict__ b1, const float* __restrict__ b2,
    const float* __restrict__ b3, const float* __restrict__ b4,
    const float* __restrict__ b5, const float* __restrict__ b6,
    const unsigned short* __restrict__ bhi, const unsigned short* __restrict__ blo,
    const unsigned short* __restrict__ b6hi, const unsigned short* __restrict__ b6lo,
    float* __restrict__ out)
{
    __shared__ __align__(16) unsigned short sthi[96][264];  // +8 pad: banks spread
    __shared__ __align__(16) unsigned short stlo[96][264];
    __shared__ float z6buf[96 * 4];

    const int tid = threadIdx.x;
    const int lane = tid & 63;
    const int wv = tid >> 6;
    const int arow = lane & 15;            // A-frag row within 16-row tile
    const int akoff = 8 * (lane >> 4);     // A-frag k offset within 32-k chunk
    const int p0 = blockIdx.x * PW;

    // ---- layer 0: 3 -> 256 elementwise
    {
        int j = tid & 255, ph = tid >> 8;
        float wt = W0[j], wx = W0[256 + j], wy = W0[512 + j], bb = b0[j];
        #pragma unroll
        for (int pp = 0; pp < 8; ++pp) {
            int p = ph * 8 + pp;
            float tv = t_[p0 + p], xv = x_[p0 + p], yv = y_[p0 + p];
            float z = tv * wt + xv * wx + yv * wy + bb;
            float sv, cv;
            __sincosf(z, &sv, &cv);
            float nv[6] = {sv, cv * wt, cv * wx, cv * wy, -sv * wx * wx, -sv * wy * wy};
            #pragma unroll
            for (int c = 0; c < 6; ++c) {
                unsigned short h = f2bf(nv[c]);
                sthi[c * 16 + p][j] = h;
                stlo[c * 16 + p][j] = f2bf(nv[c] - bf2f(h));
            }
        }
    }
    __syncthreads();

    // ---- layers 1..5: MFMA split-bf16
    const float* bias[5] = {b1, b2, b3, b4, b5};
    for (int L = 0; L < 5; ++L) {
        const u32x4* bH = (const u32x4*)bhi + L * 8192;  // 65536 u16 per layer = 8192 u32x4
        const u32x4* bL = (const u32x4*)blo + L * 8192;
        f32x4 acc[6][2];
        #pragma unroll
        for (int c = 0; c < 6; ++c)
            #pragma unroll
            for (int f = 0; f < 2; ++f)
                acc[c][f] = (f32x4){0.f, 0.f, 0.f, 0.f};

        for (int kc = 0; kc < 8; ++kc) {
            bf16x8 Bh[2], Bl[2];
            #pragma unroll
            for (int f = 0; f < 2; ++f) {
                int nf = 2 * wv + f;
                int off = (kc * 16 + nf) * 64 + lane;
                Bh[f] = __builtin_bit_cast(bf16x8, bH[off]);
                Bl[f] = __builtin_bit_cast(bf16x8, bL[off]);
            }
            #pragma unroll
            for (int c = 0; c < 6; ++c) {
                bf16x8 Ah = *(const bf16x8*)&sthi[c * 16 + arow][kc * 32 + akoff];
                bf16x8 Al = *(const bf16x8*)&stlo[c * 16 + arow][kc * 32 + akoff];
                #pragma unroll
                for (int f = 0; f < 2; ++f) {
                    acc[c][f] = __builtin_amdgcn_mfma_f32_16x16x32_bf16(Ah, Bh[f], acc[c][f], 0, 0, 0);
                    acc[c][f] = __builtin_amdgcn_mfma_f32_16x16x32_bf16(Ah, Bl[f], acc[c][f], 0, 0, 0);
                    acc[c][f] = __builtin_amdgcn_mfma_f32_16x16x32_bf16(Al, Bh[f], acc[c][f], 0, 0, 0);
                }
            }
        }
        __syncthreads();  // all A-reads done before overwrite

        const float* bb = bias[L];
        #pragma unroll
        for (int f = 0; f < 2; ++f) {
            int col = wv * 32 + f * 16 + (lane & 15);
            float bvf = bb[col];
            #pragma unroll
            for (int r = 0; r < 4; ++r) {
                int rw = (lane >> 4) * 4 + r;  // C/D row within frag
                float z = acc[0][f][r] + bvf;
                float zt = acc[1][f][r], zx = acc[2][f][r], zy = acc[3][f][r];
                float zxx = acc[4][f][r], zyy = acc[5][f][r];
                float sv, cv;
                __sincosf(z, &sv, &cv);
                float nv[6] = {sv, cv * zt, cv * zx, cv * zy,
                               cv * zxx - sv * zx * zx, cv * zyy - sv * zy * zy};
                #pragma unroll
                for (int c = 0; c < 6; ++c) {
                    unsigned short h = f2bf(nv[c]);
                    sthi[c * 16 + rw][col] = h;
                    stlo[c * 16 + rw][col] = f2bf(nv[c] - bf2f(h));
                }
            }
        }
        __syncthreads();
    }

    // ---- layer 6: 256 -> 3 (cols 3..15 are zero-padded). Wave c handles channel c.
    if (wv < 6) {
        f32x4 a6 = {0.f, 0.f, 0.f, 0.f};
        const u32x4* bH = (const u32x4*)b6hi;
        const u32x4* bL = (const u32x4*)b6lo;
        #pragma unroll
        for (int kc = 0; kc < 8; ++kc) {
            bf16x8 Bh = __builtin_bit_cast(bf16x8, bH[kc * 64 + lane]);
            bf16x8 Bl = __builtin_bit_cast(bf16x8, bL[kc * 64 + lane]);
            bf16x8 Ah = *(const bf16x8*)&sthi[wv * 16 + arow][kc * 32 + akoff];
            bf16x8 Al = *(const bf16x8*)&stlo[wv * 16 + arow][kc * 32 + akoff];
            a6 = __builtin_amdgcn_mfma_f32_16x16x32_bf16(Ah, Bh, a6, 0, 0, 0);
            a6 = __builtin_amdgcn_mfma_f32_16x16x32_bf16(Ah, Bl, a6, 0, 0, 0);
            a6 = __builtin_amdgcn_mfma_f32_16x16x32_bf16(Al, Bh, a6, 0, 0, 0);
        }
        int col = lane & 15;
        if (col < 3) {
            float badd = (wv == 0) ? b6[col] : 0.f;
            #pragma unroll
            for (int r = 0; r < 4; ++r)
                z6buf[(wv * 16 + (lane >> 4) * 4 + r) * 4 + col] = a6[r] + badd;
        }
    }
    __syncthreads();

    // ---- residuals
    if (tid < PW) {
        int p = tid, g = p0 + p;
        float u_  = z6buf[(0  + p) * 4 + 0], v_  = z6buf[(0  + p) * 4 + 1];
        float ut  = z6buf[(16 + p) * 4 + 0], vt  = z6buf[(16 + p) * 4 + 1];
        float ux  = z6buf[(32 + p) * 4 + 0], vx  = z6buf[(32 + p) * 4 + 1], px = z6buf[(32 + p) * 4 + 2];
        float uy  = z6buf[(48 + p) * 4 + 0], vy  = z6buf[(48 + p) * 4 + 1], py = z6buf[(48 + p) * 4 + 2];
        float uxx = z6buf[(64 + p) * 4 + 0], vxx = z6buf[(64 + p) * 4 + 1];
        float uyy = z6buf[(80 + p) * 4 + 0], vyy = z6buf[(80 + p) * 4 + 1];
        out[g]            = ut + (u_ * ux + v_ * uy) + px - NU * (uxx + uyy);
        out[NPTS + g]     = vt + (u_ * vx + v_ * vy) + py - NU * (vxx + vyy);
        out[2 * NPTS + g] = ux + vy;
    }
}

extern "C" void kernel_launch(void* const* d_in, const int* in_sizes, int n_in,
                              void* d_out, int out_size, void* d_ws, size_t ws_size,
                              hipStream_t stream) {
    const float* t_ = (const float*)d_in[0];
    const float* x_ = (const float*)d_in[1];
    const float* y_ = (const float*)d_in[2];
    const float* W[7];
    const float* b[7];
    for (int i = 0; i < 7; ++i) {
        W[i] = (const float*)d_in[3 + 2 * i];
        b[i] = (const float*)d_in[4 + 2 * i];
    }
    float* out = (float*)d_out;

    unsigned short* bhi  = (unsigned short*)d_ws;     // 327680 u16
    unsigned short* blo  = bhi + 5 * 65536;           // 327680 u16
    unsigned short* b6hi = blo + 5 * 65536;           // 4096 u16
    unsigned short* b6lo = b6hi + 4096;               // 4096 u16

    hipLaunchKernelGGL(prep_kernel, dim3(1296), dim3(256), 0, stream,
                       W[1], W[2], W[3], W[4], W[5], W[6], bhi, blo, b6hi, b6lo);
    hipLaunchKernelGGL(pinn_ns_mfma, dim3(NPTS / PW), dim3(512), 0, stream,
                       t_, x_, y_, W[0], b[0],
                       b[1], b[2], b[3], b[4], b[5], b[6],
                       bhi, blo, b6hi, b6lo, out);
}

// Round 3
// 205.029 us; speedup vs baseline: 7.3091x; 1.2223x over previous
//
#include <hip/hip_runtime.h>

#define NPTS 16384
#define PW 16
#define NU (1.0f / 100.0f)

typedef _Float16 f16;
typedef __attribute__((ext_vector_type(8))) _Float16 f16x8;
typedef __attribute__((ext_vector_type(4))) float f32x4;

// granule swizzle within a 64-granule (16B each) tile: bijective, applied
// identically on write and read; spreads the activation write pattern
// (granules lane_a = 16*sub + 4*q + r, varying sub/q) over all 8 bank-groups.
__device__ __forceinline__ int swz(int g) { return g ^ ((g >> 3) & 7); }

// ---- prep: W1..W5 (256x256) and W6 (256x3 zero-padded to 16 cols) -> MFMA
// B-fragment order, f16 hi + lo planes.
// B-frag (16x16x32): lane l holds B[k = kc*32 + 8*(l>>4) + j][n = nf*16 + (l&15)], j=0..7.
__global__ __launch_bounds__(256) void prep_kernel(
    const float* __restrict__ W1, const float* __restrict__ W2,
    const float* __restrict__ W3, const float* __restrict__ W4,
    const float* __restrict__ W5, const float* __restrict__ W6,
    f16* __restrict__ bhi, f16* __restrict__ blo,
    f16* __restrict__ b6hi, f16* __restrict__ b6lo)
{
    int idx = blockIdx.x * 256 + threadIdx.x;
    if (idx < 40960) {
        // (L, kc, subk) per block; col = tid. Reads: 256 consecutive floats per j -> coalesced.
        int col = idx & 255, subk = (idx >> 8) & 3, kc = (idx >> 10) & 7, L = idx >> 13;
        const float* W = (L == 0) ? W1 : (L == 1) ? W2 : (L == 2) ? W3 : (L == 3) ? W4 : W5;
        f16x8 vh, vl;
        #pragma unroll
        for (int j = 0; j < 8; ++j) {
            int k = kc * 32 + subk * 8 + j;
            float w = W[k * 256 + col];
            f16 h = (f16)w;
            vh[j] = h;
            vl[j] = (f16)(w - (float)h);
        }
        int nf = col >> 4, l15 = col & 15, lane = subk * 16 + l15;
        int dst = (((L * 8 + kc) * 16 + nf) * 64 + lane) * 8;
        *(f16x8*)(bhi + dst) = vh;
        *(f16x8*)(blo + dst) = vl;
    } else {
        int u = idx - 40960;
        if (u < 512) {
            int col = u & 15, subk = (u >> 4) & 3, kc = u >> 6;
            f16x8 vh, vl;
            #pragma unroll
            for (int j = 0; j < 8; ++j) {
                int k = kc * 32 + subk * 8 + j;
                float w = (col < 3) ? W6[k * 3 + col] : 0.f;
                f16 h = (f16)w;
                vh[j] = h;
                vl[j] = (f16)(w - (float)h);
            }
            int dst = (kc * 64 + subk * 16 + col) * 8;
            *(f16x8*)(b6hi + dst) = vh;
            *(f16x8*)(b6lo + dst) = vl;
        }
    }
}

// ---- main: PW=16 points/block, state rows = c*16+p (c: 0=val,1=dt,2=dx,3=dy,4=dxx,5=dyy).
// A state: single f16 plane, fragment-packed: afrag tile (c,kc) = 64 granules of 16B,
// granule g holds A[row = g&15][k = kc*32 + 8*(g>>4) + 0..7], stored at swz(g).
// 8 waves; wave wv owns cols [wv*32, wv*32+32) (2 n-frags).
__global__ __launch_bounds__(512) void pinn_ns_mfma(
    const float* __restrict__ t_, const float* __restrict__ x_, const float* __restrict__ y_,
    const float* __restrict__ W0, const float* __restrict__ b0,
    const float* __restrict__ b1, const float* __restrict__ b2,
    const float* __restrict__ b3, const float* __restrict__ b4,
    const float* __restrict__ b5, const float* __restrict__ b6,
    const f16* __restrict__ bhi, const f16* __restrict__ blo,
    const f16* __restrict__ b6hi, const f16* __restrict__ b6lo,
    float* __restrict__ out)
{
    __shared__ __align__(16) f16 afrag[6 * 8 * 512];   // 49152 B
    __shared__ float z6buf[96 * 4];

    const int tid = threadIdx.x;
    const int lane = tid & 63;
    const int wv = tid >> 6;
    const int gl = swz(lane);           // A-read granule (lane-linear, swizzled)
    const int p0 = blockIdx.x * PW;

    // ---- layer 0: 3 -> 256 elementwise
    {
        int j = tid & 255, ph = tid >> 8;
        float wt = W0[j], wx = W0[256 + j], wy = W0[512 + j], bb = b0[j];
        int kc = j >> 5, sub = (j >> 3) & 3, jj = j & 7;
        #pragma unroll
        for (int pp = 0; pp < 8; ++pp) {
            int p = ph * 8 + pp;
            float tv = t_[p0 + p], xv = x_[p0 + p], yv = y_[p0 + p];
            float z = tv * wt + xv * wx + yv * wy + bb;
            float sv, cv;
            __sincosf(z, &sv, &cv);
            float nv[6] = {sv, cv * wt, cv * wx, cv * wy, -sv * wx * wx, -sv * wy * wy};
            int g = swz(sub * 16 + p);
            #pragma unroll
            for (int c = 0; c < 6; ++c)
                afrag[((c * 8 + kc) * 64 + g) * 8 + jj] = (f16)nv[c];
        }
    }
    __syncthreads();

    // ---- layers 1..5: MFMA, A f16 single plane x B f16 hi/lo (2 products)
    const float* bias[5] = {b1, b2, b3, b4, b5};
    const f16x8* A = (const f16x8*)afrag;
    for (int L = 0; L < 5; ++L) {
        const f16x8* bH = (const f16x8*)bhi + L * 8192;
        const f16x8* bL = (const f16x8*)blo + L * 8192;
        f32x4 acc[6][2];
        #pragma unroll
        for (int c = 0; c < 6; ++c)
            #pragma unroll
            for (int f = 0; f < 2; ++f)
                acc[c][f] = (f32x4){0.f, 0.f, 0.f, 0.f};

        for (int kc = 0; kc < 8; ++kc) {
            f16x8 Bh[2], Bl[2];
            #pragma unroll
            for (int f = 0; f < 2; ++f) {
                int off = (kc * 16 + 2 * wv + f) * 64 + lane;
                Bh[f] = bH[off];
                Bl[f] = bL[off];
            }
            #pragma unroll
            for (int c = 0; c < 6; ++c) {
                f16x8 Ah = A[(c * 8 + kc) * 64 + gl];
                #pragma unroll
                for (int f = 0; f < 2; ++f) {
                    acc[c][f] = __builtin_amdgcn_mfma_f32_16x16x32_f16(Ah, Bh[f], acc[c][f], 0, 0, 0);
                    acc[c][f] = __builtin_amdgcn_mfma_f32_16x16x32_f16(Ah, Bl[f], acc[c][f], 0, 0, 0);
                }
            }
        }
        __syncthreads();  // all A-reads done before overwrite

        const float* bb = bias[L];
        #pragma unroll
        for (int f = 0; f < 2; ++f) {
            int col = wv * 32 + f * 16 + (lane & 15);
            int kc = wv;                       // col>>5 == wv
            int sub = (col >> 3) & 3, jj = col & 7;
            float bvf = bb[col];
            #pragma unroll
            for (int r = 0; r < 4; ++r) {
                int rw = (lane >> 4) * 4 + r;  // C/D row within frag
                float z = acc[0][f][r] + bvf;
                float zt = acc[1][f][r], zx = acc[2][f][r], zy = acc[3][f][r];
                float zxx = acc[4][f][r], zyy = acc[5][f][r];
                float sv, cv;
                __sincosf(z, &sv, &cv);
                float nv[6] = {sv, cv * zt, cv * zx, cv * zy,
                               cv * zxx - sv * zx * zx, cv * zyy - sv * zy * zy};
                int g = swz(sub * 16 + rw);
                #pragma unroll
                for (int c = 0; c < 6; ++c)
                    afrag[((c * 8 + kc) * 64 + g) * 8 + jj] = (f16)nv[c];
            }
        }
        __syncthreads();
    }

    // ---- layer 6: 256 -> 3 (cols 3..15 zero). Wave c handles channel c.
    if (wv < 6) {
        f32x4 a6 = {0.f, 0.f, 0.f, 0.f};
        const f16x8* bH = (const f16x8*)b6hi;
        const f16x8* bL = (const f16x8*)b6lo;
        #pragma unroll
        for (int kc = 0; kc < 8; ++kc) {
            f16x8 Ah = A[(wv * 8 + kc) * 64 + gl];
            a6 = __builtin_amdgcn_mfma_f32_16x16x32_f16(Ah, bH[kc * 64 + lane], a6, 0, 0, 0);
            a6 = __builtin_amdgcn_mfma_f32_16x16x32_f16(Ah, bL[kc * 64 + lane], a6, 0, 0, 0);
        }
        int col = lane & 15;
        if (col < 3) {
            float badd = (wv == 0) ? b6[col] : 0.f;
            #pragma unroll
            for (int r = 0; r < 4; ++r)
                z6buf[(wv * 16 + (lane >> 4) * 4 + r) * 4 + col] = a6[r] + badd;
        }
    }
    __syncthreads();

    // ---- residuals
    if (tid < PW) {
        int p = tid, g = p0 + p;
        float u_  = z6buf[(0  + p) * 4 + 0], v_  = z6buf[(0  + p) * 4 + 1];
        float ut  = z6buf[(16 + p) * 4 + 0], vt  = z6buf[(16 + p) * 4 + 1];
        float ux  = z6buf[(32 + p) * 4 + 0], vx  = z6buf[(32 + p) * 4 + 1], px = z6buf[(32 + p) * 4 + 2];
        float uy  = z6buf[(48 + p) * 4 + 0], vy  = z6buf[(48 + p) * 4 + 1], py = z6buf[(48 + p) * 4 + 2];
        float uxx = z6buf[(64 + p) * 4 + 0], vxx = z6buf[(64 + p) * 4 + 1];
        float uyy = z6buf[(80 + p) * 4 + 0], vyy = z6buf[(80 + p) * 4 + 1];
        out[g]            = ut + (u_ * ux + v_ * uy) + px - NU * (uxx + uyy);
        out[NPTS + g]     = vt + (u_ * vx + v_ * vy) + py - NU * (vxx + vyy);
        out[2 * NPTS + g] = ux + vy;
    }
}

extern "C" void kernel_launch(void* const* d_in, const int* in_sizes, int n_in,
                              void* d_out, int out_size, void* d_ws, size_t ws_size,
                              hipStream_t stream) {
    const float* t_ = (const float*)d_in[0];
    const float* x_ = (const float*)d_in[1];
    const float* y_ = (const float*)d_in[2];
    const float* W[7];
    const float* b[7];
    for (int i = 0; i < 7; ++i) {
        W[i] = (const float*)d_in[3 + 2 * i];
        b[i] = (const float*)d_in[4 + 2 * i];
    }
    float* out = (float*)d_out;

    f16* bhi  = (f16*)d_ws;              // 327680 f16
    f16* blo  = bhi + 5 * 65536;         // 327680 f16
    f16* b6hi = blo + 5 * 65536;         // 4096 f16
    f16* b6lo = b6hi + 4096;             // 4096 f16

    hipLaunchKernelGGL(prep_kernel, dim3(162), dim3(256), 0, stream,
                       W[1], W[2], W[3], W[4], W[5], W[6], bhi, blo, b6hi, b6lo);
    hipLaunchKernelGGL(pinn_ns_mfma, dim3(NPTS / PW), dim3(512), 0, stream,
                       t_, x_, y_, W[0], b[0],
                       b[1], b[2], b[3], b[4], b[5], b[6],
                       bhi, blo, b6hi, b6lo, out);
}

// Round 4
// 155.426 us; speedup vs baseline: 9.6417x; 1.3191x over previous
//
#include <hip/hip_runtime.h>

#define NPTS 16384
#define PW 32
#define NU (1.0f / 100.0f)

typedef _Float16 f16;
typedef __attribute__((ext_vector_type(8))) _Float16 f16x8;
typedef __attribute__((ext_vector_type(4))) float f32x4;

// granule swizzle within a 64-granule (16B each) tile: bijective, same on
// write and read; spreads activation writes over all bank groups.
__device__ __forceinline__ int swz(int g) { return g ^ ((g >> 3) & 7); }

// ---- prep: W1..W5 (256x256) and W6 (256x3 zero-padded to 16 cols) -> MFMA
// B-fragment order, single f16 plane.
// B-frag (16x16x32): lane l holds B[k = kc*32 + 8*(l>>4) + j][n = nf*16 + (l&15)], j=0..7.
__global__ __launch_bounds__(256) void prep_kernel(
    const float* __restrict__ W1, const float* __restrict__ W2,
    const float* __restrict__ W3, const float* __restrict__ W4,
    const float* __restrict__ W5, const float* __restrict__ W6,
    f16* __restrict__ bh, f16* __restrict__ b6h)
{
    int idx = blockIdx.x * 256 + threadIdx.x;
    if (idx < 40960) {
        int col = idx & 255, subk = (idx >> 8) & 3, kc = (idx >> 10) & 7, L = idx >> 13;
        const float* W = (L == 0) ? W1 : (L == 1) ? W2 : (L == 2) ? W3 : (L == 3) ? W4 : W5;
        f16x8 vh;
        #pragma unroll
        for (int j = 0; j < 8; ++j) {
            int k = kc * 32 + subk * 8 + j;
            vh[j] = (f16)W[k * 256 + col];
        }
        int nf = col >> 4, l15 = col & 15, lane = subk * 16 + l15;
        *(f16x8*)(bh + (((L * 8 + kc) * 16 + nf) * 64 + lane) * 8) = vh;
    } else {
        int u = idx - 40960;
        if (u < 512) {
            int col = u & 15, subk = (u >> 4) & 3, kc = u >> 6;
            f16x8 vh;
            #pragma unroll
            for (int j = 0; j < 8; ++j) {
                int k = kc * 32 + subk * 8 + j;
                vh[j] = (f16)((col < 3) ? W6[k * 3 + col] : 0.f);
            }
            *(f16x8*)(b6h + (kc * 64 + subk * 16 + col) * 8) = vh;
        }
    }
}

// ---- main: PW=32 points/block. State rows grouped as m-frags (c, pg):
// c = channel (0=val,1=dt,2=dx,3=dy,4=dxx,5=dyy), pg = point half (16 pts).
// A tile (c,pg,kc): 64 granules of 16B; granule g holds
// A[row = g&15 (point in pg)][k = kc*32 + 8*(g>>4) + 0..7], stored at swz(g).
// 8 waves = 2 pg-groups x 4 n-quads; wave (pg,nq) owns cols [nq*64, nq*64+64).
__global__ __launch_bounds__(512, 2) void pinn_ns_mfma(
    const float* __restrict__ t_, const float* __restrict__ x_, const float* __restrict__ y_,
    const float* __restrict__ W0, const float* __restrict__ b0,
    const float* __restrict__ b1, const float* __restrict__ b2,
    const float* __restrict__ b3, const float* __restrict__ b4,
    const float* __restrict__ b5, const float* __restrict__ b6,
    const f16* __restrict__ bh, const f16* __restrict__ b6h,
    float* __restrict__ out)
{
    __shared__ __align__(16) f16 afrag[96 * 512];   // 98304 B
    __shared__ float z6buf[6 * 32 * 4];

    const int tid = threadIdx.x;
    const int lane = tid & 63;
    const int wv = tid >> 6;
    const int pg = wv >> 2;            // point-group (0: pts 0-15, 1: pts 16-31)
    const int nq = wv & 3;             // n-quad: cols nq*64 .. +63
    const int gl = swz(lane);          // A-read granule
    const int p0 = blockIdx.x * PW;

    // ---- layer 0: 3 -> 256 elementwise
    {
        int j = tid & 255, ph = tid >> 8;
        float wt = W0[j], wx = W0[256 + j], wy = W0[512 + j], bb0 = b0[j];
        int kc = j >> 5, sub = (j >> 3) & 3, jj = j & 7;
        #pragma unroll
        for (int pp = 0; pp < 16; ++pp) {
            int p = ph * 16 + pp;
            float tv = t_[p0 + p], xv = x_[p0 + p], yv = y_[p0 + p];
            float z = tv * wt + xv * wx + yv * wy + bb0;
            float sv, cv;
            __sincosf(z, &sv, &cv);
            float nv[6] = {sv, cv * wt, cv * wx, cv * wy, -sv * wx * wx, -sv * wy * wy};
            int g = swz(sub * 16 + pp);
            #pragma unroll
            for (int c = 0; c < 6; ++c)
                afrag[(((c * 2 + ph) * 8 + kc) * 64 + g) * 8 + jj] = (f16)nv[c];
        }
    }
    __syncthreads();

    // ---- layers 1..5
    const float* bias[5] = {b1, b2, b3, b4, b5};
    const f16x8* A = (const f16x8*)afrag;
    for (int L = 0; L < 5; ++L) {
        const f16x8* bH = (const f16x8*)bh + L * 8192;
        f32x4 acc[6][4];
        #pragma unroll
        for (int c = 0; c < 6; ++c)
            #pragma unroll
            for (int f = 0; f < 4; ++f)
                acc[c][f] = (f32x4){0.f, 0.f, 0.f, 0.f};

        f16x8 Bc[4];
        #pragma unroll
        for (int f = 0; f < 4; ++f)
            Bc[f] = bH[(nq * 4 + f) * 64 + lane];

        #pragma unroll
        for (int kc = 0; kc < 8; ++kc) {
            f16x8 Bn[4];
            if (kc < 7) {
                #pragma unroll
                for (int f = 0; f < 4; ++f)
                    Bn[f] = bH[((kc + 1) * 16 + nq * 4 + f) * 64 + lane];
            }
            #pragma unroll
            for (int c = 0; c < 6; ++c) {
                f16x8 Ah = A[((c * 2 + pg) * 8 + kc) * 64 + gl];
                #pragma unroll
                for (int f = 0; f < 4; ++f)
                    acc[c][f] = __builtin_amdgcn_mfma_f32_16x16x32_f16(Ah, Bc[f], acc[c][f], 0, 0, 0);
            }
            if (kc < 7) {
                #pragma unroll
                for (int f = 0; f < 4; ++f)
                    Bc[f] = Bn[f];
            }
        }
        __syncthreads();  // all A-reads done before overwrite

        const float* bbp = bias[L];
        #pragma unroll
        for (int f = 0; f < 4; ++f) {
            int col = nq * 64 + f * 16 + (lane & 15);
            int kcw = col >> 5;
            int sub = (col >> 3) & 3, jj = col & 7;
            float bvf = bbp[col];
            #pragma unroll
            for (int r = 0; r < 4; ++r) {
                int rw = (lane >> 4) * 4 + r;
                float z = acc[0][f][r] + bvf;
                float zt = acc[1][f][r], zx = acc[2][f][r], zy = acc[3][f][r];
                float zxx = acc[4][f][r], zyy = acc[5][f][r];
                float sv, cv;
                __sincosf(z, &sv, &cv);
                float nv[6] = {sv, cv * zt, cv * zx, cv * zy,
                               cv * zxx - sv * zx * zx, cv * zyy - sv * zy * zy};
                int g = swz(sub * 16 + rw);
                #pragma unroll
                for (int c = 0; c < 6; ++c)
                    afrag[(((c * 2 + pg) * 8 + kcw) * 64 + g) * 8 + jj] = (f16)nv[c];
            }
        }
        __syncthreads();
    }

    // ---- layer 6: 256 -> 3 (cols 3..15 zero). Wave c<6 handles channel c, both pgs.
    if (wv < 6) {
        const f16x8* b6H = (const f16x8*)b6h;
        #pragma unroll
        for (int pgl = 0; pgl < 2; ++pgl) {
            f32x4 a6 = {0.f, 0.f, 0.f, 0.f};
            #pragma unroll
            for (int kc = 0; kc < 8; ++kc) {
                f16x8 Ah = A[((wv * 2 + pgl) * 8 + kc) * 64 + gl];
                a6 = __builtin_amdgcn_mfma_f32_16x16x32_f16(Ah, b6H[kc * 64 + lane], a6, 0, 0, 0);
            }
            int col = lane & 15;
            if (col < 3) {
                float badd = (wv == 0) ? b6[col] : 0.f;
                #pragma unroll
                for (int r = 0; r < 4; ++r)
                    z6buf[(wv * 32 + pgl * 16 + (lane >> 4) * 4 + r) * 4 + col] = a6[r] + badd;
            }
        }
    }
    __syncthreads();

    // ---- residuals
    if (tid < PW) {
        int p = tid, g = p0 + p;
        float u_  = z6buf[(0   + p) * 4 + 0], v_  = z6buf[(0   + p) * 4 + 1];
        float ut  = z6buf[(32  + p) * 4 + 0], vt  = z6buf[(32  + p) * 4 + 1];
        float ux  = z6buf[(64  + p) * 4 + 0], vx  = z6buf[(64  + p) * 4 + 1], px = z6buf[(64 + p) * 4 + 2];
        float uy  = z6buf[(96  + p) * 4 + 0], vy  = z6buf[(96  + p) * 4 + 1], py = z6buf[(96 + p) * 4 + 2];
        float uxx = z6buf[(128 + p) * 4 + 0], vxx = z6buf[(128 + p) * 4 + 1];
        float uyy = z6buf[(160 + p) * 4 + 0], vyy = z6buf[(160 + p) * 4 + 1];
        out[g]            = ut + (u_ * ux + v_ * uy) + px - NU * (uxx + uyy);
        out[NPTS + g]     = vt + (u_ * vx + v_ * vy) + py - NU * (vxx + vyy);
        out[2 * NPTS + g] = ux + vy;
    }
}

extern "C" void kernel_launch(void* const* d_in, const int* in_sizes, int n_in,
                              void* d_out, int out_size, void* d_ws, size_t ws_size,
                              hipStream_t stream) {
    const float* t_ = (const float*)d_in[0];
    const float* x_ = (const float*)d_in[1];
    const float* y_ = (const float*)d_in[2];
    const float* W[7];
    const float* b[7];
    for (int i = 0; i < 7; ++i) {
        W[i] = (const float*)d_in[3 + 2 * i];
        b[i] = (const float*)d_in[4 + 2 * i];
    }
    float* out = (float*)d_out;

    f16* bh  = (f16*)d_ws;               // 327680 f16
    f16* b6h = bh + 5 * 65536;           // 4096 f16

    hipLaunchKernelGGL(prep_kernel, dim3(162), dim3(256), 0, stream,
                       W[1], W[2], W[3], W[4], W[5], W[6], bh, b6h);
    hipLaunchKernelGGL(pinn_ns_mfma, dim3(NPTS / PW), dim3(512), 0, stream,
                       t_, x_, y_, W[0], b[0],
                       b[1], b[2], b[3], b[4], b[5], b[6],
                       bh, b6h, out);
}